// Round 11
// baseline (170.384 us; speedup 1.0000x reference)
//
#include <hip/hip_runtime.h>
#include <math.h>

#define T_TOK 8192
#define C_DIM 768
#define H_DIM 64
// reference MULTIPLIES by c**0.5; we work in exp2 domain: scale * log2(e)
#define SCALE_LOG2E (27.712812921102035f * 1.4426950408889634f)
#define NSPLIT 4

typedef _Float16 half8 __attribute__((ext_vector_type(8)));
typedef float floatx4 __attribute__((ext_vector_type(4)));

#define MFMA16(a, b, c) __builtin_amdgcn_mfma_f32_16x16x32_f16(a, b, c, 0, 0, 0)
// wait lgkmcnt(0) only: vmcnt=0x3F, expcnt=7, lgkm=0
#define WAIT_LGKM0() __builtin_amdgcn_s_waitcnt(0xC07F)
#define EXP2F(x) __builtin_amdgcn_exp2f(x)

// Fragment layouts in workspace (all 1KB frags, perfectly coalesced b128/lane):
//   WF[mat][kt(24)][nb(4)][hl(2)][512 f16]   = W[kt*32+quad*8+j][nb*16+l15]
//   KF[t(128)][nb(4)][ks(2)][hl(2)][512 f16] = K[t*64+nb*16+l15][ks*32+quad*8+j]
//   QF[rb(512)][ks(2)][hl(2)][512 f16]       = Q[rb*16+l15][ks*32+quad*8+j]
//   VF[t(128)][nb(4)][ks(2)][512 f16]        = V[t*64+ks*32+quad*8+j][nb*16+l15]

// ---------------------------------------------------------------------------
// Kernel 0: W fp32 -> hi/lo f16 B-frags.  288 blocks x 64 threads.
// (byte-identical to the round-10 passing version)
// ---------------------------------------------------------------------------
__global__ __launch_bounds__(64) void wconvert_kernel(
    const float* __restrict__ Wk, const float* __restrict__ Wq,
    const float* __restrict__ Wv, _Float16* __restrict__ WF)
{
    const int b = blockIdx.x;                  // 3*24*4
    const int mat = b / 96, rem = b % 96, kt = rem >> 2, nb = rem & 3;
    const int lane = threadIdx.x & 63, l15 = lane & 15, quad = lane >> 4;
    const float* __restrict__ W = (mat == 0) ? Wk : (mat == 1) ? Wq : Wv;

    half8 h, l;
#pragma unroll
    for (int j = 0; j < 8; ++j) {
        const float v = W[(kt * 32 + quad * 8 + j) * H_DIM + nb * 16 + l15];
        const _Float16 hv = (_Float16)v;
        h[j] = hv;
        l[j] = (_Float16)(v - (float)hv);
    }
    _Float16* dst = WF + ((((size_t)mat * 24 + kt) * 4 + nb) * 2) * 512 + lane * 8;
    *(half8*)dst = h;
    *(half8*)(dst + 512) = l;
}

// ---------------------------------------------------------------------------
// Kernel 1: MFMA projection — round-10 frozen body, ONE scheduling-only
// change (the class that passed in R6): token loads prefetched 4 iterations
// deep via a register FIFO (64 VGPR; proj blocks are single-wave at 3
// blocks/CU so VGPR is not an occupancy constraint).  Tokens are cold-HBM
// (~900 cy); the old 1-deep prefetch covered only ~124 cy of compute per kt
// iteration -> ~700 cy exposed x 24 iters was proj's ~45 us.  W frags stay
// 1-deep (L2-resident, ~200 cy).  ALL index math byte-identical.
// ---------------------------------------------------------------------------
__global__ __launch_bounds__(64) void proj_kernel(
    const float* __restrict__ tokens, const _Float16* __restrict__ WF,
    _Float16* __restrict__ KF, _Float16* __restrict__ QF,
    _Float16* __restrict__ VF)
{
    __shared__ float Cb[32 * 68];              // 8.5 KB
    const int b = blockIdx.x;
    const int mat = b >> 8, mi = b & 255;
    const int lane = threadIdx.x & 63, l15 = lane & 15, quad = lane >> 4;
    const int row0 = mi * 32;

    floatx4 acc[2][4];
#pragma unroll
    for (int mb = 0; mb < 2; ++mb)
#pragma unroll
        for (int nb = 0; nb < 4; ++nb) acc[mb][nb] = 0;

    const _Float16* __restrict__ wfm = WF + (size_t)mat * 24 * 4 * 2 * 512;
    const float* __restrict__ xb0 = tokens + (size_t)(row0 + l15) * C_DIM + quad * 8;
    const float* __restrict__ xb1 = tokens + (size_t)(row0 + 16 + l15) * C_DIM + quad * 8;

    // token FIFO: 4 iterations deep (kt = 0..3)
    float4 tf[4][4];
#pragma unroll
    for (int d = 0; d < 4; ++d) {
        tf[d][0] = *(const float4*)(xb0 + d * 32);
        tf[d][1] = *(const float4*)(xb0 + d * 32 + 4);
        tf[d][2] = *(const float4*)(xb1 + d * 32);
        tf[d][3] = *(const float4*)(xb1 + d * 32 + 4);
    }
    // W prefetch: 1 deep (kt = 0)
    half8 nwh[4], nwl[4];
#pragma unroll
    for (int nb = 0; nb < 4; ++nb) {
        const _Float16* wp = wfm + ((size_t)nb * 2) * 512 + lane * 8;
        nwh[nb] = *(const half8*)wp;
        nwl[nb] = (mat != 2) ? *(const half8*)(wp + 512) : nwh[nb];
    }

    for (int kt = 0; kt < 24; ++kt) {
        // stage current iteration's operands
        const int slot = kt & 3;
        const float4 x0 = tf[slot][0], x1 = tf[slot][1];
        const float4 x2 = tf[slot][2], x3 = tf[slot][3];
        half8 wh[4], wl[4];
#pragma unroll
        for (int nb = 0; nb < 4; ++nb) { wh[nb] = nwh[nb]; wl[nb] = nwl[nb]; }

        // issue next W frags (1-deep)
        const int ktn = (kt < 23) ? kt + 1 : 23;
#pragma unroll
        for (int nb = 0; nb < 4; ++nb) {
            const _Float16* wp = wfm + (((size_t)ktn * 4 + nb) * 2) * 512 + lane * 8;
            nwh[nb] = *(const half8*)wp;
            nwl[nb] = (mat != 2) ? *(const half8*)(wp + 512) : nwh[nb];
        }
        // refill token FIFO slot with kt+4
        if (kt + 4 < 24) {
            const int ktf = kt + 4;
            tf[slot][0] = *(const float4*)(xb0 + ktf * 32);
            tf[slot][1] = *(const float4*)(xb0 + ktf * 32 + 4);
            tf[slot][2] = *(const float4*)(xb1 + ktf * 32);
            tf[slot][3] = *(const float4*)(xb1 + ktf * 32 + 4);
        }

        // convert current A-tiles to hi/lo f16 (identical to round 10)
        half8 ah[2], al[2];
        {
            const float xs0[8] = {x0.x, x0.y, x0.z, x0.w, x1.x, x1.y, x1.z, x1.w};
            const float xs1[8] = {x2.x, x2.y, x2.z, x2.w, x3.x, x3.y, x3.z, x3.w};
#pragma unroll
            for (int e = 0; e < 8; ++e) {
                _Float16 hv = (_Float16)xs0[e];
                ah[0][e] = hv;
                al[0][e] = (_Float16)(xs0[e] - (float)hv);
                hv = (_Float16)xs1[e];
                ah[1][e] = hv;
                al[1][e] = (_Float16)(xs1[e] - (float)hv);
            }
        }

#pragma unroll
        for (int nb = 0; nb < 4; ++nb) {
            if (mat != 2) {
#pragma unroll
                for (int mb = 0; mb < 2; ++mb) {
                    acc[mb][nb] = MFMA16(ah[mb], wh[nb], acc[mb][nb]);
                    acc[mb][nb] = MFMA16(ah[mb], wl[nb], acc[mb][nb]);
                    acc[mb][nb] = MFMA16(al[mb], wh[nb], acc[mb][nb]);
                }
            } else {
#pragma unroll
                for (int mb = 0; mb < 2; ++mb)
                    acc[mb][nb] = MFMA16(ah[mb], wh[nb], acc[mb][nb]);
            }
        }
    }

    // C-layout -> LDS (round-4 indexing, stride 68)
#pragma unroll
    for (int mb = 0; mb < 2; ++mb)
#pragma unroll
        for (int nb = 0; nb < 4; ++nb)
#pragma unroll
            for (int r = 0; r < 4; ++r)
                Cb[(mb * 16 + quad * 4 + r) * 68 + nb * 16 + l15] = acc[mb][nb][r];
    __builtin_amdgcn_wave_barrier();
    WAIT_LGKM0();
    __builtin_amdgcn_wave_barrier();

    if (mat != 2) {                            // K (mat 0) / Q (mat 1)
#pragma unroll
        for (int nbL = 0; nbL < 2; ++nbL) {
#pragma unroll
            for (int ks = 0; ks < 2; ++ks) {
                const float* cp = Cb + (nbL * 16 + l15) * 68 + ks * 32 + quad * 8;
                const float4 c0 = *(const float4*)cp;
                const float4 c1 = *(const float4*)(cp + 4);
                const float cs[8] = {c0.x, c0.y, c0.z, c0.w, c1.x, c1.y, c1.z, c1.w};
                half8 h, l;
#pragma unroll
                for (int e = 0; e < 8; ++e) {
                    const _Float16 hv = (_Float16)cs[e];
                    h[e] = hv;
                    l[e] = (_Float16)(cs[e] - (float)hv);
                }
                _Float16* dst;
                if (mat == 0) {
                    const int t = mi >> 1, nb = (mi & 1) * 2 + nbL;
                    dst = KF + (((size_t)(t * 4 + nb) * 2 + ks) * 2) * 512 + lane * 8;
                } else {
                    const int rb = mi * 2 + nbL;
                    dst = QF + (((size_t)rb * 2 + ks) * 2) * 512 + lane * 8;
                }
                *(half8*)dst = h;
                *(half8*)(dst + 512) = l;
            }
        }
    } else {                                   // V
        const int t = mi >> 1, ks = mi & 1;
#pragma unroll
        for (int nb = 0; nb < 4; ++nb) {
            half8 h;
#pragma unroll
            for (int j = 0; j < 8; ++j)
                h[j] = (_Float16)Cb[(quad * 8 + j) * 68 + nb * 16 + l15];
            *(half8*)(VF + ((size_t)(t * 4 + nb) * 2 + ks) * 512 + lane * 8) = h;
        }
    }
}

// ---------------------------------------------------------------------------
// Kernel 2: causal flash attention.
// (byte-identical to the round-10 passing version)
// ---------------------------------------------------------------------------
__global__ __launch_bounds__(512, 2) void attn_mfma_kernel(
    const _Float16* __restrict__ QF, const _Float16* __restrict__ KF,
    const _Float16* __restrict__ VF,
    float* __restrict__ pm, float* __restrict__ pl, float* __restrict__ po)
{
    // Ps: [w(8)][mb(2)][16 rows][stride 72 f16] = 36864 B (9216 floats).
    // Merge phase reuses the same region:
    //   mO: [slot(2)][mhalf(2)][32][64] floats  @ 0     (8192 floats)
    //   mM: [slot(2)][mhalf(2)][32]             @ 8192  (128 floats)
    //   mL: [slot(2)][mhalf(2)][32]             @ 8320  (128 floats)
    __shared__ __align__(16) float smemf[9216];
    _Float16* Ps = (_Float16*)smemf;

    const int w = threadIdx.x >> 6, lane = threadIdx.x & 63;
    const int l15 = lane & 15, quad = lane >> 4;
    const int mhalf = w & 1, ss = w >> 1;

    const int b = blockIdx.x;
    const int j = b & 255, hb = b >> 8;
    const int qt = (hb == 0) ? (j >> 1) : (127 - (j >> 1));
    const int sp = (hb << 1) | (j & 1);

    const int qbase = qt * 64;
    const int wrow0 = qbase + mhalf * 32;

    // Q A-frags (hi/lo), loaded once
    half8 qh[2][2], ql[2][2];
#pragma unroll
    for (int mb = 0; mb < 2; ++mb)
#pragma unroll
        for (int ks = 0; ks < 2; ++ks) {
            const int rb = qt * 4 + mhalf * 2 + mb;
            const _Float16* qp = QF + (((size_t)rb * 2 + ks) * 2) * 512 + lane * 8;
            qh[mb][ks] = *(const half8*)qp;
            ql[mb][ks] = *(const half8*)(qp + 512);
        }

    floatx4 O[2][4];
#pragma unroll
    for (int mb = 0; mb < 2; ++mb)
#pragma unroll
        for (int nb = 0; nb < 4; ++nb) O[mb][nb] = 0;
    float mreg[2][4], lreg[2][4];
#pragma unroll
    for (int mb = 0; mb < 2; ++mb)
#pragma unroll
        for (int r = 0; r < 4; ++r) { mreg[mb][r] = -INFINITY; lreg[mb][r] = 0.f; }

    const int t0 = sp + 4 * ss;
    half8 bh[4][2], bl[4][2];
    if (t0 <= qt) {                            // preload first tile's K frags
#pragma unroll
        for (int nb = 0; nb < 4; ++nb)
#pragma unroll
            for (int ks = 0; ks < 2; ++ks) {
                const _Float16* kp =
                    KF + (((size_t)(t0 * 4 + nb) * 2 + ks) * 2) * 512 + lane * 8;
                bh[nb][ks] = *(const half8*)kp;
                bl[nb][ks] = *(const half8*)(kp + 512);
            }
    }

    for (int t = t0; t <= qt; t += 16) {
        const int kb = t * 64;

        // V frags of THIS tile: issued ~600cy before their PV use
        half8 v0r[4], v1r[4];
#pragma unroll
        for (int nb = 0; nb < 4; ++nb) {
            const _Float16* vp = VF + ((size_t)(t * 4 + nb) * 2) * 512 + lane * 8;
            v0r[nb] = *(const half8*)vp;
            v1r[nb] = *(const half8*)(vp + 512);
        }

        // S = Q K^T (hi*hi + hi*lo + lo*hi), scaled into exp2 domain
        float sv[2][4][4];
#pragma unroll
        for (int mb = 0; mb < 2; ++mb)
#pragma unroll
            for (int nb = 0; nb < 4; ++nb) {
                floatx4 s = 0;
#pragma unroll
                for (int ks = 0; ks < 2; ++ks) {
                    s = MFMA16(qh[mb][ks], bh[nb][ks], s);
                    s = MFMA16(qh[mb][ks], bl[nb][ks], s);
                    s = MFMA16(ql[mb][ks], bh[nb][ks], s);
                }
#pragma unroll
                for (int r = 0; r < 4; ++r) sv[mb][nb][r] = s[r] * SCALE_LOG2E;
            }

        // prefetch NEXT tile's K frags (current ones are dead after S)
        if (t + 16 <= qt) {
            const int tn = t + 16;
#pragma unroll
            for (int nb = 0; nb < 4; ++nb)
#pragma unroll
                for (int ks = 0; ks < 2; ++ks) {
                    const _Float16* kp =
                        KF + (((size_t)(tn * 4 + nb) * 2 + ks) * 2) * 512 + lane * 8;
                    bh[nb][ks] = *(const half8*)kp;
                    bl[nb][ks] = *(const half8*)(kp + 512);
                }
        }

        if (kb + 63 > wrow0) {                 // diagonal tile: causal mask
#pragma unroll
            for (int mb = 0; mb < 2; ++mb) {
                const int rowbase = wrow0 + mb * 16 + quad * 4;
#pragma unroll
                for (int nb = 0; nb < 4; ++nb) {
                    const int col = kb + nb * 16 + l15;
#pragma unroll
                    for (int r = 0; r < 4; ++r)
                        if (col > rowbase + r) sv[mb][nb][r] = -INFINITY;
                }
            }
        }

        // online softmax (exp2 domain)
#pragma unroll
        for (int mb = 0; mb < 2; ++mb) {
#pragma unroll
            for (int r = 0; r < 4; ++r) {
                float rm = fmaxf(fmaxf(sv[mb][0][r], sv[mb][1][r]),
                                 fmaxf(sv[mb][2][r], sv[mb][3][r]));
                rm = fmaxf(rm, __shfl_xor(rm, 1));
                rm = fmaxf(rm, __shfl_xor(rm, 2));
                rm = fmaxf(rm, __shfl_xor(rm, 4));
                rm = fmaxf(rm, __shfl_xor(rm, 8));
                const float mnew = fmaxf(mreg[mb][r], rm);
                const float alpha = EXP2F(mreg[mb][r] - mnew);   // -inf -> 0
                float psum = 0.f;
#pragma unroll
                for (int nb = 0; nb < 4; ++nb) {
                    const float p = EXP2F(sv[mb][nb][r] - mnew);  // -inf -> 0
                    psum += p;
                    Ps[(w * 2 + mb) * 1152 + (quad * 4 + r) * 72 + nb * 16 + l15] =
                        (_Float16)p;
                }
                lreg[mb][r] = lreg[mb][r] * alpha + psum;
                mreg[mb][r] = mnew;
#pragma unroll
                for (int nb = 0; nb < 4; ++nb) O[mb][nb][r] *= alpha;
            }
        }

        // P: C-layout -> A-layout via wave-private LDS
        __builtin_amdgcn_wave_barrier();
        WAIT_LGKM0();
        __builtin_amdgcn_wave_barrier();
        half8 pa0[2], pa1[2];
#pragma unroll
        for (int mb = 0; mb < 2; ++mb) {
            const _Float16* pp = Ps + (w * 2 + mb) * 1152 + l15 * 72 + quad * 8;
            pa0[mb] = *(const half8*)pp;
            pa1[mb] = *(const half8*)(pp + 32);
        }

        // PV with the V frags loaded at tile top
#pragma unroll
        for (int nb = 0; nb < 4; ++nb) {
#pragma unroll
            for (int mb = 0; mb < 2; ++mb) {
                O[mb][nb] = MFMA16(pa0[mb], v0r[nb], O[mb][nb]);
                O[mb][nb] = MFMA16(pa1[mb], v1r[nb], O[mb][nb]);
            }
        }
        __builtin_amdgcn_wave_barrier();
    }

    // row-sum l across the 16-lane group (lane-local partials are exact
    // because alpha factors are row-uniform)
#pragma unroll
    for (int mb = 0; mb < 2; ++mb)
#pragma unroll
        for (int r = 0; r < 4; ++r) {
            float s = lreg[mb][r];
            s += __shfl_xor(s, 1);
            s += __shfl_xor(s, 2);
            s += __shfl_xor(s, 4);
            s += __shfl_xor(s, 8);
            lreg[mb][r] = s;
        }

    // ---- 2-round subsplit merge (proven pattern applied twice) ----
    __syncthreads();                           // Ps now dead; reuse as buffers
    // Round A: ss in {2,3} publish to slot ss-2
    if (ss >= 2) {
        const int slot = ss - 2;
#pragma unroll
        for (int mb = 0; mb < 2; ++mb)
#pragma unroll
            for (int r = 0; r < 4; ++r) {
                const int row32 = mb * 16 + quad * 4 + r;
                const int sidx = (slot * 2 + mhalf) * 32 + row32;
#pragma unroll
                for (int nb = 0; nb < 4; ++nb)
                    smemf[sidx * 64 + nb * 16 + l15] = O[mb][nb][r];
                if (l15 == 0) {
                    smemf[8192 + sidx] = mreg[mb][r];
                    smemf[8320 + sidx] = lreg[mb][r];
                }
            }
    }
    __syncthreads();
    if (ss < 2) {                              // ss0 <- slot0(ss2), ss1 <- slot1(ss3)
        const int slot = ss;
#pragma unroll
        for (int mb = 0; mb < 2; ++mb)
#pragma unroll
            for (int r = 0; r < 4; ++r) {
                const int row32 = mb * 16 + quad * 4 + r;
                const int sidx = (slot * 2 + mhalf) * 32 + row32;
                const float m1 = mreg[mb][r], l1 = lreg[mb][r];
                const float m2 = smemf[8192 + sidx];
                const float l2 = smemf[8320 + sidx];
                const float mm = fmaxf(m1, m2);
                const float a1 = (m1 == -INFINITY) ? 0.f : EXP2F(m1 - mm);
                const float a2 = (m2 == -INFINITY) ? 0.f : EXP2F(m2 - mm);
#pragma unroll
                for (int nb = 0; nb < 4; ++nb)
                    O[mb][nb][r] = O[mb][nb][r] * a1 +
                                   smemf[sidx * 64 + nb * 16 + l15] * a2;
                mreg[mb][r] = mm;
                lreg[mb][r] = l1 * a1 + l2 * a2;
            }
    }
    __syncthreads();
    // Round B: ss==1 publish merged state to slot 0
    if (ss == 1) {
#pragma unroll
        for (int mb = 0; mb < 2; ++mb)
#pragma unroll
            for (int r = 0; r < 4; ++r) {
                const int row32 = mb * 16 + quad * 4 + r;
                const int sidx = mhalf * 32 + row32;   // slot 0
#pragma unroll
                for (int nb = 0; nb < 4; ++nb)
                    smemf[sidx * 64 + nb * 16 + l15] = O[mb][nb][r];
                if (l15 == 0) {
                    smemf[8192 + sidx] = mreg[mb][r];
                    smemf[8320 + sidx] = lreg[mb][r];
                }
            }
    }
    __syncthreads();
    if (ss == 0) {                             // final merge + write partials
        const int pidx = qt * NSPLIT + sp;
#pragma unroll
        for (int mb = 0; mb < 2; ++mb)
#pragma unroll
            for (int r = 0; r < 4; ++r) {
                const int row32 = mb * 16 + quad * 4 + r;
                const int sidx = mhalf * 32 + row32;   // slot 0
                const float m1 = mreg[mb][r], l1 = lreg[mb][r];
                const float m2 = smemf[8192 + sidx];
                const float l2 = smemf[8320 + sidx];
                const float mm = fmaxf(m1, m2);
                const float a1 = (m1 == -INFINITY) ? 0.f : EXP2F(m1 - mm);
                const float a2 = (m2 == -INFINITY) ? 0.f : EXP2F(m2 - mm);
                const int row = mhalf * 32 + row32;
                float* dst = po + ((size_t)pidx * 64 + row) * 64;
#pragma unroll
                for (int nb = 0; nb < 4; ++nb)
                    dst[nb * 16 + l15] =
                        O[mb][nb][r] * a1 + smemf[sidx * 64 + nb * 16 + l15] * a2;
                if (l15 == 0) {
                    pm[pidx * 64 + row] = mm;
                    pl[pidx * 64 + row] = l1 * a1 + l2 * a2;
                }
            }
    }
}

// ---------------------------------------------------------------------------
// Kernel 3: merge the NSPLIT split-partials per row (exp2 domain).
// float4-vectorized: each thread handles 4 consecutive d of one row (same
// per-element math as the round-10 version; po reads and out writes are
// 16B coalesced; L computed once per 4 outputs).
// ---------------------------------------------------------------------------
__global__ __launch_bounds__(256) void combine_kernel(
    const float* __restrict__ pm, const float* __restrict__ pl,
    const float* __restrict__ po, float* __restrict__ out)
{
    const int vid = blockIdx.x * 256 + threadIdx.x;    // over T*H/4
    const int row = vid >> 4;                          // 16 float4 per row
    const int d4  = vid & 15;
    const int qt  = row >> 6;
    const int r   = row & 63;

    float mm = -INFINITY;
#pragma unroll
    for (int s = 0; s < NSPLIT; ++s)
        mm = fmaxf(mm, pm[(qt * NSPLIT + s) * 64 + r]);
    float L = 0.f;
    float4 val = make_float4(0.f, 0.f, 0.f, 0.f);
#pragma unroll
    for (int s = 0; s < NSPLIT; ++s) {
        const int p = (qt * NSPLIT + s) * 64 + r;
        const float mp = pm[p];
        const float sc = (mp > -INFINITY) ? EXP2F(mp - mm) : 0.f;
        L += pl[p] * sc;
        const float4 v = *(const float4*)(po + (size_t)p * H_DIM + d4 * 4);
        val.x += v.x * sc; val.y += v.y * sc;
        val.z += v.z * sc; val.w += v.w * sc;
    }
    const float inv = 1.0f / L;
    float4 o; o.x = val.x * inv; o.y = val.y * inv;
    o.z = val.z * inv; o.w = val.w * inv;
    *(float4*)(out + (size_t)row * H_DIM + d4 * 4) = o;
}

// ---------------------------------------------------------------------------
extern "C" void kernel_launch(void* const* d_in, const int* in_sizes, int n_in,
                              void* d_out, int out_size, void* d_ws, size_t ws_size,
                              hipStream_t stream)
{
    const float* tokens = (const float*)d_in[0];
    const float* Wk = (const float*)d_in[1];
    const float* Wq = (const float*)d_in[2];
    const float* Wv = (const float*)d_in[3];
    float* out = (float*)d_out;

    // ws layout (bytes), total 14.25 MB:
    //   WF @0 (576KB) | KF @1MB (2MB) | QF @3MB (2MB) | VF @5MB (1MB)
    //   pm @6MB (128KB) | pl @6.125MB (128KB) | po @6.25MB (8MB)
    char* ws = (char*)d_ws;
    const size_t MB = 1024 * 1024;
    _Float16* WF = (_Float16*)(ws + 0 * MB);
    _Float16* KF = (_Float16*)(ws + 1 * MB);
    _Float16* QF = (_Float16*)(ws + 3 * MB);
    _Float16* VF = (_Float16*)(ws + 5 * MB);
    float* pm = (float*)(ws + 6 * MB);
    float* pl = (float*)(ws + 6 * MB + 128 * 1024);
    float* po = (float*)(ws + 6 * MB + 256 * 1024);

    wconvert_kernel<<<288, 64, 0, stream>>>(Wk, Wq, Wv, WF);

    proj_kernel<<<768, 64, 0, stream>>>(tokens, WF, KF, QF, VF);

    attn_mfma_kernel<<<128 * NSPLIT, 512, 0, stream>>>(QF, KF, VF, pm, pl, po);

    combine_kernel<<<T_TOK * H_DIM / 4 / 256, 256, 0, stream>>>(pm, pl, po, out);
}

// Round 12
// 143.719 us; speedup vs baseline: 1.1855x; 1.1855x over previous
//
#include <hip/hip_runtime.h>
#include <math.h>

#define T_TOK 8192
#define C_DIM 768
#define H_DIM 64
// reference MULTIPLIES by c**0.5; we work in exp2 domain: scale * log2(e)
#define SCALE_LOG2E (27.712812921102035f * 1.4426950408889634f)
#define NSPLIT 4

typedef _Float16 half8 __attribute__((ext_vector_type(8)));
typedef float floatx4 __attribute__((ext_vector_type(4)));

#define MFMA16(a, b, c) __builtin_amdgcn_mfma_f32_16x16x32_f16(a, b, c, 0, 0, 0)
// wait lgkmcnt(0) only: vmcnt=0x3F, expcnt=7, lgkm=0
#define WAIT_LGKM0() __builtin_amdgcn_s_waitcnt(0xC07F)
#define EXP2F(x) __builtin_amdgcn_exp2f(x)

// Fragment layouts in workspace (all 1KB frags, perfectly coalesced b128/lane):
//   WF[mat][kt(24)][nb(4)][hl(2)][512 f16]   = W[kt*32+quad*8+j][nb*16+l15]
//   KF[t(128)][nb(4)][ks(2)][hl(2)][512 f16] = K[t*64+nb*16+l15][ks*32+quad*8+j]
//   QF[rb(512)][ks(2)][hl(2)][512 f16]       = Q[rb*16+l15][ks*32+quad*8+j]
//   VF[t(128)][nb(4)][ks(2)][512 f16]        = V[t*64+ks*32+quad*8+j][nb*16+l15]

// ---------------------------------------------------------------------------
// Kernel 0: W fp32 -> hi/lo f16 B-frags.  288 blocks x 64 threads.
// (byte-identical to the round-10 passing version)
// ---------------------------------------------------------------------------
__global__ __launch_bounds__(64) void wconvert_kernel(
    const float* __restrict__ Wk, const float* __restrict__ Wq,
    const float* __restrict__ Wv, _Float16* __restrict__ WF)
{
    const int b = blockIdx.x;                  // 3*24*4
    const int mat = b / 96, rem = b % 96, kt = rem >> 2, nb = rem & 3;
    const int lane = threadIdx.x & 63, l15 = lane & 15, quad = lane >> 4;
    const float* __restrict__ W = (mat == 0) ? Wk : (mat == 1) ? Wq : Wv;

    half8 h, l;
#pragma unroll
    for (int j = 0; j < 8; ++j) {
        const float v = W[(kt * 32 + quad * 8 + j) * H_DIM + nb * 16 + l15];
        const _Float16 hv = (_Float16)v;
        h[j] = hv;
        l[j] = (_Float16)(v - (float)hv);
    }
    _Float16* dst = WF + ((((size_t)mat * 24 + kt) * 4 + nb) * 2) * 512 + lane * 8;
    *(half8*)dst = h;
    *(half8*)(dst + 512) = l;
}

// ---------------------------------------------------------------------------
// Kernel 1: MFMA projection — round-11 body, ONE change: the kt loop is
// FULLY UNROLLED.  Round 11's `tf[kt & 3]` runtime index forced the 4-deep
// token FIFO into scratch (WRITE_SIZE 5 -> 50 MB, proj 45 -> 66 us): a
// dynamically-indexed local array cannot live in VGPRs.  With full unroll,
// slot/ktn/guards are compile-time, the FIFO stays in registers (~180 VGPR,
// harmless for single-wave blocks), and 4 token loads remain in flight,
// covering ~500+ cy of the ~900 cy HBM latency.
// ---------------------------------------------------------------------------
__global__ __launch_bounds__(64) void proj_kernel(
    const float* __restrict__ tokens, const _Float16* __restrict__ WF,
    _Float16* __restrict__ KF, _Float16* __restrict__ QF,
    _Float16* __restrict__ VF)
{
    __shared__ float Cb[32 * 68];              // 8.5 KB
    const int b = blockIdx.x;
    const int mat = b >> 8, mi = b & 255;
    const int lane = threadIdx.x & 63, l15 = lane & 15, quad = lane >> 4;
    const int row0 = mi * 32;

    floatx4 acc[2][4];
#pragma unroll
    for (int mb = 0; mb < 2; ++mb)
#pragma unroll
        for (int nb = 0; nb < 4; ++nb) acc[mb][nb] = 0;

    const _Float16* __restrict__ wfm = WF + (size_t)mat * 24 * 4 * 2 * 512;
    const float* __restrict__ xb0 = tokens + (size_t)(row0 + l15) * C_DIM + quad * 8;
    const float* __restrict__ xb1 = tokens + (size_t)(row0 + 16 + l15) * C_DIM + quad * 8;

    // token FIFO: 4 iterations deep (kt = 0..3)
    float4 tf[4][4];
#pragma unroll
    for (int d = 0; d < 4; ++d) {
        tf[d][0] = *(const float4*)(xb0 + d * 32);
        tf[d][1] = *(const float4*)(xb0 + d * 32 + 4);
        tf[d][2] = *(const float4*)(xb1 + d * 32);
        tf[d][3] = *(const float4*)(xb1 + d * 32 + 4);
    }
    // W prefetch: 1 deep (kt = 0)
    half8 nwh[4], nwl[4];
#pragma unroll
    for (int nb = 0; nb < 4; ++nb) {
        const _Float16* wp = wfm + ((size_t)nb * 2) * 512 + lane * 8;
        nwh[nb] = *(const half8*)wp;
        nwl[nb] = (mat != 2) ? *(const half8*)(wp + 512) : nwh[nb];
    }

#pragma unroll
    for (int kt = 0; kt < 24; ++kt) {
        // stage current iteration's operands (slot is compile-time now)
        const int slot = kt & 3;
        const float4 x0 = tf[slot][0], x1 = tf[slot][1];
        const float4 x2 = tf[slot][2], x3 = tf[slot][3];
        half8 wh[4], wl[4];
#pragma unroll
        for (int nb = 0; nb < 4; ++nb) { wh[nb] = nwh[nb]; wl[nb] = nwl[nb]; }

        // issue next W frags (1-deep)
        const int ktn = (kt < 23) ? kt + 1 : 23;
#pragma unroll
        for (int nb = 0; nb < 4; ++nb) {
            const _Float16* wp = wfm + (((size_t)ktn * 4 + nb) * 2) * 512 + lane * 8;
            nwh[nb] = *(const half8*)wp;
            nwl[nb] = (mat != 2) ? *(const half8*)(wp + 512) : nwh[nb];
        }
        // refill token FIFO slot with kt+4 (guard is compile-time)
        if (kt + 4 < 24) {
            const int ktf = kt + 4;
            tf[slot][0] = *(const float4*)(xb0 + ktf * 32);
            tf[slot][1] = *(const float4*)(xb0 + ktf * 32 + 4);
            tf[slot][2] = *(const float4*)(xb1 + ktf * 32);
            tf[slot][3] = *(const float4*)(xb1 + ktf * 32 + 4);
        }

        // convert current A-tiles to hi/lo f16 (identical to round 10)
        half8 ah[2], al[2];
        {
            const float xs0[8] = {x0.x, x0.y, x0.z, x0.w, x1.x, x1.y, x1.z, x1.w};
            const float xs1[8] = {x2.x, x2.y, x2.z, x2.w, x3.x, x3.y, x3.z, x3.w};
#pragma unroll
            for (int e = 0; e < 8; ++e) {
                _Float16 hv = (_Float16)xs0[e];
                ah[0][e] = hv;
                al[0][e] = (_Float16)(xs0[e] - (float)hv);
                hv = (_Float16)xs1[e];
                ah[1][e] = hv;
                al[1][e] = (_Float16)(xs1[e] - (float)hv);
            }
        }

#pragma unroll
        for (int nb = 0; nb < 4; ++nb) {
            if (mat != 2) {
#pragma unroll
                for (int mb = 0; mb < 2; ++mb) {
                    acc[mb][nb] = MFMA16(ah[mb], wh[nb], acc[mb][nb]);
                    acc[mb][nb] = MFMA16(ah[mb], wl[nb], acc[mb][nb]);
                    acc[mb][nb] = MFMA16(al[mb], wh[nb], acc[mb][nb]);
                }
            } else {
#pragma unroll
                for (int mb = 0; mb < 2; ++mb)
                    acc[mb][nb] = MFMA16(ah[mb], wh[nb], acc[mb][nb]);
            }
        }
    }

    // C-layout -> LDS (round-4 indexing, stride 68)
#pragma unroll
    for (int mb = 0; mb < 2; ++mb)
#pragma unroll
        for (int nb = 0; nb < 4; ++nb)
#pragma unroll
            for (int r = 0; r < 4; ++r)
                Cb[(mb * 16 + quad * 4 + r) * 68 + nb * 16 + l15] = acc[mb][nb][r];
    __builtin_amdgcn_wave_barrier();
    WAIT_LGKM0();
    __builtin_amdgcn_wave_barrier();

    if (mat != 2) {                            // K (mat 0) / Q (mat 1)
#pragma unroll
        for (int nbL = 0; nbL < 2; ++nbL) {
#pragma unroll
            for (int ks = 0; ks < 2; ++ks) {
                const float* cp = Cb + (nbL * 16 + l15) * 68 + ks * 32 + quad * 8;
                const float4 c0 = *(const float4*)cp;
                const float4 c1 = *(const float4*)(cp + 4);
                const float cs[8] = {c0.x, c0.y, c0.z, c0.w, c1.x, c1.y, c1.z, c1.w};
                half8 h, l;
#pragma unroll
                for (int e = 0; e < 8; ++e) {
                    const _Float16 hv = (_Float16)cs[e];
                    h[e] = hv;
                    l[e] = (_Float16)(cs[e] - (float)hv);
                }
                _Float16* dst;
                if (mat == 0) {
                    const int t = mi >> 1, nb = (mi & 1) * 2 + nbL;
                    dst = KF + (((size_t)(t * 4 + nb) * 2 + ks) * 2) * 512 + lane * 8;
                } else {
                    const int rb = mi * 2 + nbL;
                    dst = QF + (((size_t)rb * 2 + ks) * 2) * 512 + lane * 8;
                }
                *(half8*)dst = h;
                *(half8*)(dst + 512) = l;
            }
        }
    } else {                                   // V
        const int t = mi >> 1, ks = mi & 1;
#pragma unroll
        for (int nb = 0; nb < 4; ++nb) {
            half8 h;
#pragma unroll
            for (int j = 0; j < 8; ++j)
                h[j] = (_Float16)Cb[(quad * 8 + j) * 68 + nb * 16 + l15];
            *(half8*)(VF + ((size_t)(t * 4 + nb) * 2 + ks) * 512 + lane * 8) = h;
        }
    }
}

// ---------------------------------------------------------------------------
// Kernel 2: causal flash attention.
// (byte-identical to the round-10 passing version)
// ---------------------------------------------------------------------------
__global__ __launch_bounds__(512, 2) void attn_mfma_kernel(
    const _Float16* __restrict__ QF, const _Float16* __restrict__ KF,
    const _Float16* __restrict__ VF,
    float* __restrict__ pm, float* __restrict__ pl, float* __restrict__ po)
{
    // Ps: [w(8)][mb(2)][16 rows][stride 72 f16] = 36864 B (9216 floats).
    // Merge phase reuses the same region:
    //   mO: [slot(2)][mhalf(2)][32][64] floats  @ 0     (8192 floats)
    //   mM: [slot(2)][mhalf(2)][32]             @ 8192  (128 floats)
    //   mL: [slot(2)][mhalf(2)][32]             @ 8320  (128 floats)
    __shared__ __align__(16) float smemf[9216];
    _Float16* Ps = (_Float16*)smemf;

    const int w = threadIdx.x >> 6, lane = threadIdx.x & 63;
    const int l15 = lane & 15, quad = lane >> 4;
    const int mhalf = w & 1, ss = w >> 1;

    const int b = blockIdx.x;
    const int j = b & 255, hb = b >> 8;
    const int qt = (hb == 0) ? (j >> 1) : (127 - (j >> 1));
    const int sp = (hb << 1) | (j & 1);

    const int qbase = qt * 64;
    const int wrow0 = qbase + mhalf * 32;

    // Q A-frags (hi/lo), loaded once
    half8 qh[2][2], ql[2][2];
#pragma unroll
    for (int mb = 0; mb < 2; ++mb)
#pragma unroll
        for (int ks = 0; ks < 2; ++ks) {
            const int rb = qt * 4 + mhalf * 2 + mb;
            const _Float16* qp = QF + (((size_t)rb * 2 + ks) * 2) * 512 + lane * 8;
            qh[mb][ks] = *(const half8*)qp;
            ql[mb][ks] = *(const half8*)(qp + 512);
        }

    floatx4 O[2][4];
#pragma unroll
    for (int mb = 0; mb < 2; ++mb)
#pragma unroll
        for (int nb = 0; nb < 4; ++nb) O[mb][nb] = 0;
    float mreg[2][4], lreg[2][4];
#pragma unroll
    for (int mb = 0; mb < 2; ++mb)
#pragma unroll
        for (int r = 0; r < 4; ++r) { mreg[mb][r] = -INFINITY; lreg[mb][r] = 0.f; }

    const int t0 = sp + 4 * ss;
    half8 bh[4][2], bl[4][2];
    if (t0 <= qt) {                            // preload first tile's K frags
#pragma unroll
        for (int nb = 0; nb < 4; ++nb)
#pragma unroll
            for (int ks = 0; ks < 2; ++ks) {
                const _Float16* kp =
                    KF + (((size_t)(t0 * 4 + nb) * 2 + ks) * 2) * 512 + lane * 8;
                bh[nb][ks] = *(const half8*)kp;
                bl[nb][ks] = *(const half8*)(kp + 512);
            }
    }

    for (int t = t0; t <= qt; t += 16) {
        const int kb = t * 64;

        // V frags of THIS tile: issued ~600cy before their PV use
        half8 v0r[4], v1r[4];
#pragma unroll
        for (int nb = 0; nb < 4; ++nb) {
            const _Float16* vp = VF + ((size_t)(t * 4 + nb) * 2) * 512 + lane * 8;
            v0r[nb] = *(const half8*)vp;
            v1r[nb] = *(const half8*)(vp + 512);
        }

        // S = Q K^T (hi*hi + hi*lo + lo*hi), scaled into exp2 domain
        float sv[2][4][4];
#pragma unroll
        for (int mb = 0; mb < 2; ++mb)
#pragma unroll
            for (int nb = 0; nb < 4; ++nb) {
                floatx4 s = 0;
#pragma unroll
                for (int ks = 0; ks < 2; ++ks) {
                    s = MFMA16(qh[mb][ks], bh[nb][ks], s);
                    s = MFMA16(qh[mb][ks], bl[nb][ks], s);
                    s = MFMA16(ql[mb][ks], bh[nb][ks], s);
                }
#pragma unroll
                for (int r = 0; r < 4; ++r) sv[mb][nb][r] = s[r] * SCALE_LOG2E;
            }

        // prefetch NEXT tile's K frags (current ones are dead after S)
        if (t + 16 <= qt) {
            const int tn = t + 16;
#pragma unroll
            for (int nb = 0; nb < 4; ++nb)
#pragma unroll
                for (int ks = 0; ks < 2; ++ks) {
                    const _Float16* kp =
                        KF + (((size_t)(tn * 4 + nb) * 2 + ks) * 2) * 512 + lane * 8;
                    bh[nb][ks] = *(const half8*)kp;
                    bl[nb][ks] = *(const half8*)(kp + 512);
                }
        }

        if (kb + 63 > wrow0) {                 // diagonal tile: causal mask
#pragma unroll
            for (int mb = 0; mb < 2; ++mb) {
                const int rowbase = wrow0 + mb * 16 + quad * 4;
#pragma unroll
                for (int nb = 0; nb < 4; ++nb) {
                    const int col = kb + nb * 16 + l15;
#pragma unroll
                    for (int r = 0; r < 4; ++r)
                        if (col > rowbase + r) sv[mb][nb][r] = -INFINITY;
                }
            }
        }

        // online softmax (exp2 domain)
#pragma unroll
        for (int mb = 0; mb < 2; ++mb) {
#pragma unroll
            for (int r = 0; r < 4; ++r) {
                float rm = fmaxf(fmaxf(sv[mb][0][r], sv[mb][1][r]),
                                 fmaxf(sv[mb][2][r], sv[mb][3][r]));
                rm = fmaxf(rm, __shfl_xor(rm, 1));
                rm = fmaxf(rm, __shfl_xor(rm, 2));
                rm = fmaxf(rm, __shfl_xor(rm, 4));
                rm = fmaxf(rm, __shfl_xor(rm, 8));
                const float mnew = fmaxf(mreg[mb][r], rm);
                const float alpha = EXP2F(mreg[mb][r] - mnew);   // -inf -> 0
                float psum = 0.f;
#pragma unroll
                for (int nb = 0; nb < 4; ++nb) {
                    const float p = EXP2F(sv[mb][nb][r] - mnew);  // -inf -> 0
                    psum += p;
                    Ps[(w * 2 + mb) * 1152 + (quad * 4 + r) * 72 + nb * 16 + l15] =
                        (_Float16)p;
                }
                lreg[mb][r] = lreg[mb][r] * alpha + psum;
                mreg[mb][r] = mnew;
#pragma unroll
                for (int nb = 0; nb < 4; ++nb) O[mb][nb][r] *= alpha;
            }
        }

        // P: C-layout -> A-layout via wave-private LDS
        __builtin_amdgcn_wave_barrier();
        WAIT_LGKM0();
        __builtin_amdgcn_wave_barrier();
        half8 pa0[2], pa1[2];
#pragma unroll
        for (int mb = 0; mb < 2; ++mb) {
            const _Float16* pp = Ps + (w * 2 + mb) * 1152 + l15 * 72 + quad * 8;
            pa0[mb] = *(const half8*)pp;
            pa1[mb] = *(const half8*)(pp + 32);
        }

        // PV with the V frags loaded at tile top
#pragma unroll
        for (int nb = 0; nb < 4; ++nb) {
#pragma unroll
            for (int mb = 0; mb < 2; ++mb) {
                O[mb][nb] = MFMA16(pa0[mb], v0r[nb], O[mb][nb]);
                O[mb][nb] = MFMA16(pa1[mb], v1r[nb], O[mb][nb]);
            }
        }
        __builtin_amdgcn_wave_barrier();
    }

    // row-sum l across the 16-lane group (lane-local partials are exact
    // because alpha factors are row-uniform)
#pragma unroll
    for (int mb = 0; mb < 2; ++mb)
#pragma unroll
        for (int r = 0; r < 4; ++r) {
            float s = lreg[mb][r];
            s += __shfl_xor(s, 1);
            s += __shfl_xor(s, 2);
            s += __shfl_xor(s, 4);
            s += __shfl_xor(s, 8);
            lreg[mb][r] = s;
        }

    // ---- 2-round subsplit merge (proven pattern applied twice) ----
    __syncthreads();                           // Ps now dead; reuse as buffers
    // Round A: ss in {2,3} publish to slot ss-2
    if (ss >= 2) {
        const int slot = ss - 2;
#pragma unroll
        for (int mb = 0; mb < 2; ++mb)
#pragma unroll
            for (int r = 0; r < 4; ++r) {
                const int row32 = mb * 16 + quad * 4 + r;
                const int sidx = (slot * 2 + mhalf) * 32 + row32;
#pragma unroll
                for (int nb = 0; nb < 4; ++nb)
                    smemf[sidx * 64 + nb * 16 + l15] = O[mb][nb][r];
                if (l15 == 0) {
                    smemf[8192 + sidx] = mreg[mb][r];
                    smemf[8320 + sidx] = lreg[mb][r];
                }
            }
    }
    __syncthreads();
    if (ss < 2) {                              // ss0 <- slot0(ss2), ss1 <- slot1(ss3)
        const int slot = ss;
#pragma unroll
        for (int mb = 0; mb < 2; ++mb)
#pragma unroll
            for (int r = 0; r < 4; ++r) {
                const int row32 = mb * 16 + quad * 4 + r;
                const int sidx = (slot * 2 + mhalf) * 32 + row32;
                const float m1 = mreg[mb][r], l1 = lreg[mb][r];
                const float m2 = smemf[8192 + sidx];
                const float l2 = smemf[8320 + sidx];
                const float mm = fmaxf(m1, m2);
                const float a1 = (m1 == -INFINITY) ? 0.f : EXP2F(m1 - mm);
                const float a2 = (m2 == -INFINITY) ? 0.f : EXP2F(m2 - mm);
#pragma unroll
                for (int nb = 0; nb < 4; ++nb)
                    O[mb][nb][r] = O[mb][nb][r] * a1 +
                                   smemf[sidx * 64 + nb * 16 + l15] * a2;
                mreg[mb][r] = mm;
                lreg[mb][r] = l1 * a1 + l2 * a2;
            }
    }
    __syncthreads();
    // Round B: ss==1 publish merged state to slot 0
    if (ss == 1) {
#pragma unroll
        for (int mb = 0; mb < 2; ++mb)
#pragma unroll
            for (int r = 0; r < 4; ++r) {
                const int row32 = mb * 16 + quad * 4 + r;
                const int sidx = mhalf * 32 + row32;   // slot 0
#pragma unroll
                for (int nb = 0; nb < 4; ++nb)
                    smemf[sidx * 64 + nb * 16 + l15] = O[mb][nb][r];
                if (l15 == 0) {
                    smemf[8192 + sidx] = mreg[mb][r];
                    smemf[8320 + sidx] = lreg[mb][r];
                }
            }
    }
    __syncthreads();
    if (ss == 0) {                             // final merge + write partials
        const int pidx = qt * NSPLIT + sp;
#pragma unroll
        for (int mb = 0; mb < 2; ++mb)
#pragma unroll
            for (int r = 0; r < 4; ++r) {
                const int row32 = mb * 16 + quad * 4 + r;
                const int sidx = mhalf * 32 + row32;   // slot 0
                const float m1 = mreg[mb][r], l1 = lreg[mb][r];
                const float m2 = smemf[8192 + sidx];
                const float l2 = smemf[8320 + sidx];
                const float mm = fmaxf(m1, m2);
                const float a1 = (m1 == -INFINITY) ? 0.f : EXP2F(m1 - mm);
                const float a2 = (m2 == -INFINITY) ? 0.f : EXP2F(m2 - mm);
                const int row = mhalf * 32 + row32;
                float* dst = po + ((size_t)pidx * 64 + row) * 64;
#pragma unroll
                for (int nb = 0; nb < 4; ++nb)
                    dst[nb * 16 + l15] =
                        O[mb][nb][r] * a1 + smemf[sidx * 64 + nb * 16 + l15] * a2;
                if (l15 == 0) {
                    pm[pidx * 64 + row] = mm;
                    pl[pidx * 64 + row] = l1 * a1 + l2 * a2;
                }
            }
    }
}

// ---------------------------------------------------------------------------
// Kernel 3: merge the NSPLIT split-partials per row (exp2 domain).
// (byte-identical to the round-11 passing float4 version)
// ---------------------------------------------------------------------------
__global__ __launch_bounds__(256) void combine_kernel(
    const float* __restrict__ pm, const float* __restrict__ pl,
    const float* __restrict__ po, float* __restrict__ out)
{
    const int vid = blockIdx.x * 256 + threadIdx.x;    // over T*H/4
    const int row = vid >> 4;                          // 16 float4 per row
    const int d4  = vid & 15;
    const int qt  = row >> 6;
    const int r   = row & 63;

    float mm = -INFINITY;
#pragma unroll
    for (int s = 0; s < NSPLIT; ++s)
        mm = fmaxf(mm, pm[(qt * NSPLIT + s) * 64 + r]);
    float L = 0.f;
    float4 val = make_float4(0.f, 0.f, 0.f, 0.f);
#pragma unroll
    for (int s = 0; s < NSPLIT; ++s) {
        const int p = (qt * NSPLIT + s) * 64 + r;
        const float mp = pm[p];
        const float sc = (mp > -INFINITY) ? EXP2F(mp - mm) : 0.f;
        L += pl[p] * sc;
        const float4 v = *(const float4*)(po + (size_t)p * H_DIM + d4 * 4);
        val.x += v.x * sc; val.y += v.y * sc;
        val.z += v.z * sc; val.w += v.w * sc;
    }
    const float inv = 1.0f / L;
    float4 o; o.x = val.x * inv; o.y = val.y * inv;
    o.z = val.z * inv; o.w = val.w * inv;
    *(float4*)(out + (size_t)row * H_DIM + d4 * 4) = o;
}

// ---------------------------------------------------------------------------
extern "C" void kernel_launch(void* const* d_in, const int* in_sizes, int n_in,
                              void* d_out, int out_size, void* d_ws, size_t ws_size,
                              hipStream_t stream)
{
    const float* tokens = (const float*)d_in[0];
    const float* Wk = (const float*)d_in[1];
    const float* Wq = (const float*)d_in[2];
    const float* Wv = (const float*)d_in[3];
    float* out = (float*)d_out;

    // ws layout (bytes), total 14.25 MB:
    //   WF @0 (576KB) | KF @1MB (2MB) | QF @3MB (2MB) | VF @5MB (1MB)
    //   pm @6MB (128KB) | pl @6.125MB (128KB) | po @6.25MB (8MB)
    char* ws = (char*)d_ws;
    const size_t MB = 1024 * 1024;
    _Float16* WF = (_Float16*)(ws + 0 * MB);
    _Float16* KF = (_Float16*)(ws + 1 * MB);
    _Float16* QF = (_Float16*)(ws + 3 * MB);
    _Float16* VF = (_Float16*)(ws + 5 * MB);
    float* pm = (float*)(ws + 6 * MB);
    float* pl = (float*)(ws + 6 * MB + 128 * 1024);
    float* po = (float*)(ws + 6 * MB + 256 * 1024);

    wconvert_kernel<<<288, 64, 0, stream>>>(Wk, Wq, Wv, WF);

    proj_kernel<<<768, 64, 0, stream>>>(tokens, WF, KF, QF, VF);

    attn_mfma_kernel<<<128 * NSPLIT, 512, 0, stream>>>(QF, KF, VF, pm, pl, po);

    combine_kernel<<<T_TOK * H_DIM / 4 / 256, 256, 0, stream>>>(pm, pl, po, out);
}